// Round 10
// baseline (310.111 us; speedup 1.0000x reference)
//
#include <hip/hip_runtime.h>

#define NN 100000
#define NE 800000
#define HD 64
#define BK 128                            // nodes per bucket
#define NBUCK ((NN + BK - 1) / BK)        // 782
#define PA_EPT 16                         // edges per thread in passA
#define PA_NB ((NE + 256 * PA_EPT - 1) / (256 * PA_EPT))   // 196
#define LDW 68                            // padded leading dim: 68 f = 272 B

__device__ __forceinline__ int load_idx(const void* ei, int i, bool is32) {
    if (is32) return ((const int*)ei)[i];
    return (int)(((const long long*)ei)[i]);
}

__device__ __forceinline__ unsigned short f2bf(float f) {   // round-to-nearest
    unsigned u = __float_as_uint(f);
    return (unsigned short)((u + 0x7FFFu + ((u >> 16) & 1u)) >> 16);
}

// expand uint4 (8 packed bf16, feature order) and accumulate into 2 float4s
__device__ __forceinline__ void bfacc(const uint4& u, float4& a, float4& b) {
    a.x += __uint_as_float(u.x << 16);
    a.y += __uint_as_float(u.x & 0xFFFF0000u);
    a.z += __uint_as_float(u.y << 16);
    a.w += __uint_as_float(u.y & 0xFFFF0000u);
    b.x += __uint_as_float(u.z << 16);
    b.y += __uint_as_float(u.z & 0xFFFF0000u);
    b.z += __uint_as_float(u.w << 16);
    b.w += __uint_as_float(u.w & 0xFFFF0000u);
}

// zero bucket counters + flag, then dtype-detect (int32 vs int64) in one launch.
__global__ void k_initdet(const void* ei, int* bcnt, int* flag) {
    __shared__ int bad;
    int t = threadIdx.x;
    if (t == 0) bad = 0;
    if (t < NBUCK) bcnt[t] = 0;
    __syncthreads();
    const long long* p = (const long long*)ei;
    for (int i = t; i < 4096; i += 1024) {
        long long v = p[i];
        if (v < 0 || v >= (long long)NN) bad = 1;
    }
    __syncthreads();
    if (t == 0) *flag = bad ? 1 : 0;
}

// global bucket histogram via per-block LDS histograms
__global__ __launch_bounds__(256) void k_pass0(const void* ei, const int* flag,
                                               int* bcnt) {
    __shared__ int h[NBUCK];
    for (int i = threadIdx.x; i < NBUCK; i += 256) h[i] = 0;
    __syncthreads();
    bool is32 = (*flag != 0);
    int stride = gridDim.x * 256;
    for (int e = blockIdx.x * 256 + threadIdx.x; e < NE; e += stride) {
        int dst = load_idx(ei, NE + e, is32);
        atomicAdd(&h[dst >> 7], 1);
    }
    __syncthreads();
    for (int i = threadIdx.x; i < NBUCK; i += 256) {
        int v = h[i];
        if (v) atomicAdd(&bcnt[i], v);
    }
}

// scan 782 bucket counts -> offs[0..NBUCK], curs[b]=offs[b]
__global__ __launch_bounds__(256) void k_scan1(const int* __restrict__ bcnt,
                                               int* __restrict__ offs,
                                               int* __restrict__ curs) {
    __shared__ int sc[256];
    int t = threadIdx.x;
    int v[4], s = 0;
#pragma unroll
    for (int i = 0; i < 4; ++i) {
        int b = t * 4 + i;
        v[i] = (b < NBUCK) ? bcnt[b] : 0;
        s += v[i];
    }
    sc[t] = s;
    __syncthreads();
    for (int off = 1; off < 256; off <<= 1) {
        int add = (t >= off) ? sc[t - off] : 0;
        __syncthreads();
        sc[t] += add;
        __syncthreads();
    }
    int run = sc[t] - s;   // exclusive prefix
#pragma unroll
    for (int i = 0; i < 4; ++i) {
        int b = t * 4 + i;
        if (b < NBUCK) { offs[b] = run; curs[b] = run; }
        run += v[i];
    }
    if (t == 255) offs[NBUCK] = sc[255];
}

// bin edges into bucket-major ebuf; packed word = src | (dst&127)<<17
__global__ __launch_bounds__(256) void k_passA(const void* ei, const int* flag,
                                               int* curs, unsigned* ebuf) {
    __shared__ int h[NBUCK];
    __shared__ int base[NBUCK];
    for (int i = threadIdx.x; i < NBUCK; i += 256) h[i] = 0;
    __syncthreads();
    bool is32 = (*flag != 0);
    int e0 = blockIdx.x * (256 * PA_EPT);
    int src[PA_EPT], dst[PA_EPT];
#pragma unroll
    for (int i = 0; i < PA_EPT; ++i) {
        int e = e0 + i * 256 + threadIdx.x;
        if (e < NE) {
            src[i] = load_idx(ei, e, is32);
            dst[i] = load_idx(ei, NE + e, is32);
            atomicAdd(&h[dst[i] >> 7], 1);
        } else dst[i] = -1;
    }
    __syncthreads();
    for (int i = threadIdx.x; i < NBUCK; i += 256) {
        int v = h[i];
        base[i] = v ? atomicAdd(&curs[i], v) : 0;
        h[i] = 0;                      // reuse as local rank counter
    }
    __syncthreads();
#pragma unroll
    for (int i = 0; i < PA_EPT; ++i) {
        if (dst[i] >= 0) {
            int b = dst[i] >> 7;
            int p = base[b] + atomicAdd(&h[b], 1);
            ebuf[p] = (unsigned)src[i] | ((unsigned)(dst[i] & 127) << 17);
        }
    }
}

// per-bucket counting sort -> per-node CSR (noffs, csr_src) + dinv.
__global__ __launch_bounds__(256) void k_passB(const unsigned* __restrict__ ebuf,
                                               const int* __restrict__ offs,
                                               int* __restrict__ noffs,
                                               int* __restrict__ csr_src,
                                               float* __restrict__ dinv) {
    __shared__ int cnt[BK];
    __shared__ int sc[BK];
    __shared__ int nbase[BK];
    __shared__ int rank[BK];
    int bk = blockIdx.x;
    int t = threadIdx.x;
    if (t < BK) { cnt[t] = 0; rank[t] = 0; }
    __syncthreads();
    int rs = offs[bk], re = offs[bk + 1];
    for (int i = rs + t; i < re; i += 256)
        atomicAdd(&cnt[ebuf[i] >> 17], 1);
    __syncthreads();
    if (t < BK) sc[t] = cnt[t];
    __syncthreads();
    for (int off = 1; off < BK; off <<= 1) {       // inclusive scan of cnt
        int v = 0;
        if (t < BK && t >= off) v = sc[t - off];
        __syncthreads();
        if (t < BK) sc[t] += v;
        __syncthreads();
    }
    if (t < BK) {
        int node = bk * BK + t;
        int nb = rs + sc[t] - cnt[t];              // exclusive prefix
        nbase[t] = nb;
        if (node < NN) {
            noffs[node] = nb;
            dinv[node] = rsqrtf((float)(cnt[t] + 1));
        }
    }
    if (bk == NBUCK - 1 && t == 0) noffs[NN] = re;
    __syncthreads();
    for (int i = rs + t; i < re; i += 256) {
        unsigned w = ebuf[i];
        int dl = w >> 17;
        int p = nbase[dl] + atomicAdd(&rank[dl], 1);
        csr_src[p] = (int)(w & 0x1FFFFu);
    }
}

// H = dinv * (X @ W) as bf16 rows (layer-0 only). 128 rows/block; thread =
// 8 rows (strided by 16) x 4 cols; unroll 1 + launch_bounds(256,4) (R6
// lesson: full unroll -> 256 VGPR, occupancy collapse).
template <bool BIAS, bool PRE, bool BF16OUT>
__global__ __launch_bounds__(256, 4) void k_gemm(const float* __restrict__ X,
                                                 const float* __restrict__ W,
                                                 const float* __restrict__ bias,
                                                 const float* __restrict__ dinv,
                                                 void* __restrict__ Hout, int n) {
    __shared__ float Ws[64 * LDW];     // 17.4 KB
    __shared__ float Xs[128 * LDW];    // 34.8 KB
    int t = threadIdx.x;
    int row0 = blockIdx.x * 128;
    const float4* X4 = (const float4*)X;
    for (int i = t; i < 64 * 16; i += 256) {       // W: 1024 float4
        float4 v = ((const float4*)W)[i];
        *(float4*)&Ws[(i >> 4) * LDW + (i & 15) * 4] = v;
    }
    for (int i = t; i < 128 * 16; i += 256) {      // X tile: 2048 float4
        int r = row0 + (i >> 4);
        float4 v = (r < n) ? X4[(size_t)r * 16 + (i & 15)]
                           : make_float4(0.f, 0.f, 0.f, 0.f);
        *(float4*)&Xs[(i >> 4) * LDW + (i & 15) * 4] = v;
    }
    __syncthreads();
    int tc = (t & 15) * 4;       // 4 output cols
    int rbase = t >> 4;          // rows rbase + 16*i, i=0..7
    float4 acc[8] = {};
#pragma unroll 1
    for (int k = 0; k < 64; k += 4) {
        float4 wv[4], xv[8];
#pragma unroll
        for (int kk = 0; kk < 4; ++kk)
            wv[kk] = *(const float4*)&Ws[(k + kk) * LDW + tc];
#pragma unroll
        for (int i = 0; i < 8; ++i)
            xv[i] = *(const float4*)&Xs[(rbase + 16 * i) * LDW + k];
#pragma unroll
        for (int i = 0; i < 8; ++i) {
            acc[i].x += xv[i].x * wv[0].x + xv[i].y * wv[1].x
                      + xv[i].z * wv[2].x + xv[i].w * wv[3].x;
            acc[i].y += xv[i].x * wv[0].y + xv[i].y * wv[1].y
                      + xv[i].z * wv[2].y + xv[i].w * wv[3].y;
            acc[i].z += xv[i].x * wv[0].z + xv[i].y * wv[1].z
                      + xv[i].z * wv[2].z + xv[i].w * wv[3].z;
            acc[i].w += xv[i].x * wv[0].w + xv[i].y * wv[1].w
                      + xv[i].z * wv[2].w + xv[i].w * wv[3].w;
        }
    }
    float4 bv = make_float4(0.f, 0.f, 0.f, 0.f);
    if (BIAS) bv = *(const float4*)&bias[tc];
#pragma unroll
    for (int i = 0; i < 8; ++i) {
        int r = row0 + rbase + 16 * i;
        if (r < n) {
            float s = PRE ? dinv[r] : 1.f;
            float4 o;
            o.x = (acc[i].x + bv.x) * s;
            o.y = (acc[i].y + bv.y) * s;
            o.z = (acc[i].z + bv.z) * s;
            o.w = (acc[i].w + bv.w) * s;
            if (BF16OUT) {
                ushort4 p;
                p.x = f2bf(o.x); p.y = f2bf(o.y); p.z = f2bf(o.z); p.w = f2bf(o.w);
                ((ushort4*)Hout)[(size_t)r * 16 + (t & 15)] = p;
            } else {
                ((float4*)Hout)[(size_t)r * 16 + (t & 15)] = o;
            }
        }
    }
}

// Fused aggregation + next-layer GEMM. Phase 1 = R9's verified gather (wave =
// 2 nodes, 16 gathers in flight); the relu'd rows go to wave-local LDS (in-
// wave LDS round-trip; no barrier — phase 2 only reads the own wave's rows).
// Phase 2: half-wave computes row@Wt (Wt = W^T in LDS, staged once, one
// barrier at kernel start). MODE 0: emit bf16 dinv*(row@W) for next layer.
// MODE 1: emit out0 = relu row (graded) and out1 = row@Wl + bl (graded).
template <int MODE>
__global__ __launch_bounds__(256) void k_fused(const uint4* __restrict__ Hb,
                                               const int* __restrict__ noffs,
                                               const int* __restrict__ csr_src,
                                               const float* __restrict__ dinv,
                                               const float4* __restrict__ b4,
                                               const float* __restrict__ Wn,
                                               const float* __restrict__ bl,
                                               unsigned short* __restrict__ HbOut,
                                               float4* __restrict__ out0,
                                               float* __restrict__ out1) {
    __shared__ float Wt[64 * LDW];     // W^T, 17.4 KB
    __shared__ float rows[8 * LDW];    // 8 relu'd rows, 2.2 KB
    __shared__ float dvs[8];
    __shared__ float bls[64];
    int t = threadIdx.x;
    // stage Wt (transpose W) — float4 global reads, scalar LDS writes
#pragma unroll
    for (int j = 0; j < 4; ++j) {
        int i = t + 256 * j;                   // chunk in [0,1024)
        int k = i >> 4;
        int c4 = (i & 15) * 4;
        float4 v = ((const float4*)Wn)[i];
        Wt[(c4 + 0) * LDW + k] = v.x;
        Wt[(c4 + 1) * LDW + k] = v.y;
        Wt[(c4 + 2) * LDW + k] = v.z;
        Wt[(c4 + 3) * LDW + k] = v.w;
    }
    if (MODE == 1 && t < 64) bls[t] = bl[t];
    __syncthreads();                           // the only barrier

    // ---- phase 1: gather + reduce (R9 structure) ----
    int lane = t & 63;
    int half = lane >> 5, hl = lane & 31;
    int c = hl >> 3, q = hl & 7;
    int nl = (t >> 6) * 2 + half;              // node slot 0..7 in block
    int node = blockIdx.x * 8 + nl;
    float dv = 0.f;
    float4 alo = make_float4(0.f, 0.f, 0.f, 0.f);
    float4 ahi = make_float4(0.f, 0.f, 0.f, 0.f);
    if (node < NN) {
        dv = dinv[node];
        if (c == 0) {                          // self-loop (prescaled)
            uint4 u = Hb[(size_t)node * 8 + q];
            bfacc(u, alo, ahi);
        }
        int e0 = noffs[node], e1 = noffs[node + 1];
        int e = e0 + c;
        for (; e + 4 < e1; e += 8) {
            uint4 u0 = Hb[(size_t)csr_src[e] * 8 + q];
            uint4 u1 = Hb[(size_t)csr_src[e + 4] * 8 + q];
            bfacc(u0, alo, ahi);
            bfacc(u1, alo, ahi);
        }
        if (e < e1) {
            uint4 u = Hb[(size_t)csr_src[e] * 8 + q];
            bfacc(u, alo, ahi);
        }
    }
#pragma unroll
    for (int off = 8; off < 32; off <<= 1) {   // reduce 4 clusters per half
        alo.x += __shfl_xor(alo.x, off, 64);
        alo.y += __shfl_xor(alo.y, off, 64);
        alo.z += __shfl_xor(alo.z, off, 64);
        alo.w += __shfl_xor(alo.w, off, 64);
        ahi.x += __shfl_xor(ahi.x, off, 64);
        ahi.y += __shfl_xor(ahi.y, off, 64);
        ahi.z += __shfl_xor(ahi.z, off, 64);
        ahi.w += __shfl_xor(ahi.w, off, 64);
    }
    if (c == 0 && node < NN) {                 // relu'd row -> wave-local LDS
        float4 b0v = b4[2 * q], b1v = b4[2 * q + 1];
        float4 r0, r1;
        r0.x = fmaxf(alo.x * dv + b0v.x, 0.f);
        r0.y = fmaxf(alo.y * dv + b0v.y, 0.f);
        r0.z = fmaxf(alo.z * dv + b0v.z, 0.f);
        r0.w = fmaxf(alo.w * dv + b0v.w, 0.f);
        r1.x = fmaxf(ahi.x * dv + b1v.x, 0.f);
        r1.y = fmaxf(ahi.y * dv + b1v.y, 0.f);
        r1.z = fmaxf(ahi.z * dv + b1v.z, 0.f);
        r1.w = fmaxf(ahi.w * dv + b1v.w, 0.f);
        *(float4*)&rows[nl * LDW + 8 * q]     = r0;
        *(float4*)&rows[nl * LDW + 8 * q + 4] = r1;
        if (MODE == 1) {
            out0[(size_t)node * 16 + 2 * q]     = r0;
            out0[(size_t)node * 16 + 2 * q + 1] = r1;
        }
        if (q == 0) dvs[nl] = dv;
    }

    // ---- phase 2: row @ Wt (wave-local; reads only this wave's rows) ----
    int n2 = t >> 5;                           // 0..7; same wave's node slots
    int c0 = t & 31, c1 = c0 + 32;
    int node2 = blockIdx.x * 8 + n2;
    float o0 = 0.f, o1 = 0.f;
#pragma unroll 4
    for (int k = 0; k < 64; k += 4) {
        float4 rv = *(const float4*)&rows[n2 * LDW + k];
        float4 w0 = *(const float4*)&Wt[c0 * LDW + k];
        float4 w1 = *(const float4*)&Wt[c1 * LDW + k];
        o0 += rv.x * w0.x + rv.y * w0.y + rv.z * w0.z + rv.w * w0.w;
        o1 += rv.x * w1.x + rv.y * w1.y + rv.z * w1.z + rv.w * w1.w;
    }
    if (node2 < NN) {
        if (MODE == 0) {
            float s = dvs[n2];
            HbOut[(size_t)node2 * 64 + c0] = f2bf(o0 * s);
            HbOut[(size_t)node2 * 64 + c1] = f2bf(o1 * s);
        } else {
            out1[(size_t)node2 * 64 + c0] = o0 + bls[c0];
            out1[(size_t)node2 * 64 + c1] = o1 + bls[c1];
        }
    }
}

extern "C" void kernel_launch(void* const* d_in, const int* in_sizes, int n_in,
                              void* d_out, int out_size, void* d_ws, size_t ws_size,
                              hipStream_t stream) {
    const float* x  = (const float*)d_in[0];
    const void*  ei = d_in[1];               // edge_index, dtype detected on device
    const float* W0 = (const float*)d_in[3];
    const float* b0 = (const float*)d_in[4];
    const float* W1 = (const float*)d_in[5];
    const float* b1 = (const float*)d_in[6];
    const float* W2 = (const float*)d_in[7];
    const float* b2 = (const float*)d_in[8];
    const float* Wl = (const float*)d_in[9];
    const float* bl = (const float*)d_in[10];

    char* ws = (char*)d_ws;
    int*      flag    = (int*)(ws);
    int*      bcnt    = (int*)(ws + 256);
    int*      offs    = (int*)(ws + 4352);        // 783 ints
    int*      curs    = (int*)(ws + 8448);        // 782 ints
    float*    dinv    = (float*)(ws + 12544);     // 400000 B
    int*      noffs   = (int*)(ws + 412672);      // 100001 ints
    int*      csr_src = (int*)(ws + 812800);      // 3.2 MB
    unsigned short* HbA = (unsigned short*)(ws + 4100096);    // 12.8 MB
    unsigned short* HbB = (unsigned short*)(ws + 16900096);   // 12.8 MB

    float* out0 = (float*)d_out;             // graded relu output (h3)
    float* out1 = out0 + (size_t)NN * HD;    // graded linear output
    unsigned* ebuf = (unsigned*)out1;        // bucket-major edges; dies pre-GEMM0

    int gG = (NN + 127) / 128;               // 782 gemm blocks
    int gF = (NN + 7) / 8;                   // 12500 fused blocks (8 nodes each)

    // ---- preprocessing: bucket bin + in-bucket counting sort -> CSR ----
    k_initdet<<<1, 1024, 0, stream>>>(ei, bcnt, flag);
    k_pass0<<<128, 256, 0, stream>>>(ei, flag, bcnt);
    k_scan1<<<1, 256, 0, stream>>>(bcnt, offs, curs);
    k_passA<<<PA_NB, 256, 0, stream>>>(ei, flag, curs, ebuf);
    k_passB<<<NBUCK, 256, 0, stream>>>(ebuf, offs, noffs, csr_src, dinv);

    // ---- layer 0 GEMM: HbA = dinv * (x @ W0), bf16 ----
    k_gemm<false, true, true><<<gG, 256, 0, stream>>>(x, W0, nullptr, dinv,
                                                      (void*)HbA, NN);
    // ---- fused layer 1: agg(HbA)+b0+relu, @W1*dinv -> HbB ----
    k_fused<0><<<gF, 256, 0, stream>>>((const uint4*)HbA, noffs, csr_src, dinv,
                                       (const float4*)b0, W1, nullptr,
                                       HbB, nullptr, nullptr);
    // ---- fused layer 2: agg(HbB)+b1+relu, @W2*dinv -> HbA ----
    k_fused<0><<<gF, 256, 0, stream>>>((const uint4*)HbB, noffs, csr_src, dinv,
                                       (const float4*)b1, W2, nullptr,
                                       HbA, nullptr, nullptr);
    // ---- fused final: agg(HbA)+b2+relu -> out0 ; row@Wl+bl -> out1 ----
    k_fused<1><<<gF, 256, 0, stream>>>((const uint4*)HbA, noffs, csr_src, dinv,
                                       (const float4*)b2, Wl, bl,
                                       nullptr, (float4*)out0, out1);
}

// Round 11
// 288.333 us; speedup vs baseline: 1.0755x; 1.0755x over previous
//
#include <hip/hip_runtime.h>

#define NN 100000
#define NE 800000
#define HD 64
#define BK 128                            // nodes per bucket
#define NBUCK ((NN + BK - 1) / BK)        // 782
#define PA_EPT 16                         // edges per thread in passA
#define PA_NB ((NE + 256 * PA_EPT - 1) / (256 * PA_EPT))   // 196
#define LDW 68                            // padded leading dim: 68 f = 272 B

__device__ __forceinline__ int load_idx(const void* ei, int i, bool is32) {
    if (is32) return ((const int*)ei)[i];
    return (int)(((const long long*)ei)[i]);
}

__device__ __forceinline__ unsigned short f2bf(float f) {   // round-to-nearest
    unsigned u = __float_as_uint(f);
    return (unsigned short)((u + 0x7FFFu + ((u >> 16) & 1u)) >> 16);
}

// expand uint4 (8 packed bf16, feature order) and accumulate into 2 float4s
__device__ __forceinline__ void bfacc(const uint4& u, float4& a, float4& b) {
    a.x += __uint_as_float(u.x << 16);
    a.y += __uint_as_float(u.x & 0xFFFF0000u);
    a.z += __uint_as_float(u.y << 16);
    a.w += __uint_as_float(u.y & 0xFFFF0000u);
    b.x += __uint_as_float(u.z << 16);
    b.y += __uint_as_float(u.z & 0xFFFF0000u);
    b.z += __uint_as_float(u.w << 16);
    b.w += __uint_as_float(u.w & 0xFFFF0000u);
}

// zero bucket counters + flag, then dtype-detect (int32 vs int64) in one launch.
__global__ void k_initdet(const void* ei, int* bcnt, int* flag) {
    __shared__ int bad;
    int t = threadIdx.x;
    if (t == 0) bad = 0;
    if (t < NBUCK) bcnt[t] = 0;
    __syncthreads();
    const long long* p = (const long long*)ei;
    for (int i = t; i < 4096; i += 1024) {
        long long v = p[i];
        if (v < 0 || v >= (long long)NN) bad = 1;
    }
    __syncthreads();
    if (t == 0) *flag = bad ? 1 : 0;
}

// global bucket histogram via per-block LDS histograms
__global__ __launch_bounds__(256) void k_pass0(const void* ei, const int* flag,
                                               int* bcnt) {
    __shared__ int h[NBUCK];
    for (int i = threadIdx.x; i < NBUCK; i += 256) h[i] = 0;
    __syncthreads();
    bool is32 = (*flag != 0);
    int stride = gridDim.x * 256;
    for (int e = blockIdx.x * 256 + threadIdx.x; e < NE; e += stride) {
        int dst = load_idx(ei, NE + e, is32);
        atomicAdd(&h[dst >> 7], 1);
    }
    __syncthreads();
    for (int i = threadIdx.x; i < NBUCK; i += 256) {
        int v = h[i];
        if (v) atomicAdd(&bcnt[i], v);
    }
}

// scan 782 bucket counts -> offs[0..NBUCK], curs[b]=offs[b]
__global__ __launch_bounds__(256) void k_scan1(const int* __restrict__ bcnt,
                                               int* __restrict__ offs,
                                               int* __restrict__ curs) {
    __shared__ int sc[256];
    int t = threadIdx.x;
    int v[4], s = 0;
#pragma unroll
    for (int i = 0; i < 4; ++i) {
        int b = t * 4 + i;
        v[i] = (b < NBUCK) ? bcnt[b] : 0;
        s += v[i];
    }
    sc[t] = s;
    __syncthreads();
    for (int off = 1; off < 256; off <<= 1) {
        int add = (t >= off) ? sc[t - off] : 0;
        __syncthreads();
        sc[t] += add;
        __syncthreads();
    }
    int run = sc[t] - s;   // exclusive prefix
#pragma unroll
    for (int i = 0; i < 4; ++i) {
        int b = t * 4 + i;
        if (b < NBUCK) { offs[b] = run; curs[b] = run; }
        run += v[i];
    }
    if (t == 255) offs[NBUCK] = sc[255];
}

// bin edges into bucket-major ebuf; packed word = src | (dst&127)<<17
__global__ __launch_bounds__(256) void k_passA(const void* ei, const int* flag,
                                               int* curs, unsigned* ebuf) {
    __shared__ int h[NBUCK];
    __shared__ int base[NBUCK];
    for (int i = threadIdx.x; i < NBUCK; i += 256) h[i] = 0;
    __syncthreads();
    bool is32 = (*flag != 0);
    int e0 = blockIdx.x * (256 * PA_EPT);
    int src[PA_EPT], dst[PA_EPT];
#pragma unroll
    for (int i = 0; i < PA_EPT; ++i) {
        int e = e0 + i * 256 + threadIdx.x;
        if (e < NE) {
            src[i] = load_idx(ei, e, is32);
            dst[i] = load_idx(ei, NE + e, is32);
            atomicAdd(&h[dst[i] >> 7], 1);
        } else dst[i] = -1;
    }
    __syncthreads();
    for (int i = threadIdx.x; i < NBUCK; i += 256) {
        int v = h[i];
        base[i] = v ? atomicAdd(&curs[i], v) : 0;
        h[i] = 0;                      // reuse as local rank counter
    }
    __syncthreads();
#pragma unroll
    for (int i = 0; i < PA_EPT; ++i) {
        if (dst[i] >= 0) {
            int b = dst[i] >> 7;
            int p = base[b] + atomicAdd(&h[b], 1);
            ebuf[p] = (unsigned)src[i] | ((unsigned)(dst[i] & 127) << 17);
        }
    }
}

// per-bucket counting sort -> per-node CSR (noffs, csr_src) + dinv.
__global__ __launch_bounds__(256) void k_passB(const unsigned* __restrict__ ebuf,
                                               const int* __restrict__ offs,
                                               int* __restrict__ noffs,
                                               int* __restrict__ csr_src,
                                               float* __restrict__ dinv) {
    __shared__ int cnt[BK];
    __shared__ int sc[BK];
    __shared__ int nbase[BK];
    __shared__ int rank[BK];
    int bk = blockIdx.x;
    int t = threadIdx.x;
    if (t < BK) { cnt[t] = 0; rank[t] = 0; }
    __syncthreads();
    int rs = offs[bk], re = offs[bk + 1];
    for (int i = rs + t; i < re; i += 256)
        atomicAdd(&cnt[ebuf[i] >> 17], 1);
    __syncthreads();
    if (t < BK) sc[t] = cnt[t];
    __syncthreads();
    for (int off = 1; off < BK; off <<= 1) {       // inclusive scan of cnt
        int v = 0;
        if (t < BK && t >= off) v = sc[t - off];
        __syncthreads();
        if (t < BK) sc[t] += v;
        __syncthreads();
    }
    if (t < BK) {
        int node = bk * BK + t;
        int nb = rs + sc[t] - cnt[t];              // exclusive prefix
        nbase[t] = nb;
        if (node < NN) {
            noffs[node] = nb;
            dinv[node] = rsqrtf((float)(cnt[t] + 1));
        }
    }
    if (bk == NBUCK - 1 && t == 0) noffs[NN] = re;
    __syncthreads();
    for (int i = rs + t; i < re; i += 256) {
        unsigned w = ebuf[i];
        int dl = w >> 17;
        int p = nbase[dl] + atomicAdd(&rank[dl], 1);
        csr_src[p] = (int)(w & 0x1FFFFu);
    }
}

// H = dinv * (X @ W) as bf16 rows (layer-0 only). 128 rows/block; thread =
// 8 rows (strided by 16) x 4 cols; unroll 1 + launch_bounds(256,4) (R6
// lesson: full unroll -> 256 VGPR, occupancy collapse).
template <bool BIAS, bool PRE, bool BF16OUT>
__global__ __launch_bounds__(256, 4) void k_gemm(const float* __restrict__ X,
                                                 const float* __restrict__ W,
                                                 const float* __restrict__ bias,
                                                 const float* __restrict__ dinv,
                                                 void* __restrict__ Hout, int n) {
    __shared__ float Ws[64 * LDW];     // 17.4 KB
    __shared__ float Xs[128 * LDW];    // 34.8 KB
    int t = threadIdx.x;
    int row0 = blockIdx.x * 128;
    const float4* X4 = (const float4*)X;
    for (int i = t; i < 64 * 16; i += 256) {       // W: 1024 float4
        float4 v = ((const float4*)W)[i];
        *(float4*)&Ws[(i >> 4) * LDW + (i & 15) * 4] = v;
    }
    for (int i = t; i < 128 * 16; i += 256) {      // X tile: 2048 float4
        int r = row0 + (i >> 4);
        float4 v = (r < n) ? X4[(size_t)r * 16 + (i & 15)]
                           : make_float4(0.f, 0.f, 0.f, 0.f);
        *(float4*)&Xs[(i >> 4) * LDW + (i & 15) * 4] = v;
    }
    __syncthreads();
    int tc = (t & 15) * 4;       // 4 output cols
    int rbase = t >> 4;          // rows rbase + 16*i, i=0..7
    float4 acc[8] = {};
#pragma unroll 1
    for (int k = 0; k < 64; k += 4) {
        float4 wv[4], xv[8];
#pragma unroll
        for (int kk = 0; kk < 4; ++kk)
            wv[kk] = *(const float4*)&Ws[(k + kk) * LDW + tc];
#pragma unroll
        for (int i = 0; i < 8; ++i)
            xv[i] = *(const float4*)&Xs[(rbase + 16 * i) * LDW + k];
#pragma unroll
        for (int i = 0; i < 8; ++i) {
            acc[i].x += xv[i].x * wv[0].x + xv[i].y * wv[1].x
                      + xv[i].z * wv[2].x + xv[i].w * wv[3].x;
            acc[i].y += xv[i].x * wv[0].y + xv[i].y * wv[1].y
                      + xv[i].z * wv[2].y + xv[i].w * wv[3].y;
            acc[i].z += xv[i].x * wv[0].z + xv[i].y * wv[1].z
                      + xv[i].z * wv[2].z + xv[i].w * wv[3].z;
            acc[i].w += xv[i].x * wv[0].w + xv[i].y * wv[1].w
                      + xv[i].z * wv[2].w + xv[i].w * wv[3].w;
        }
    }
    float4 bv = make_float4(0.f, 0.f, 0.f, 0.f);
    if (BIAS) bv = *(const float4*)&bias[tc];
#pragma unroll
    for (int i = 0; i < 8; ++i) {
        int r = row0 + rbase + 16 * i;
        if (r < n) {
            float s = PRE ? dinv[r] : 1.f;
            float4 o;
            o.x = (acc[i].x + bv.x) * s;
            o.y = (acc[i].y + bv.y) * s;
            o.z = (acc[i].z + bv.z) * s;
            o.w = (acc[i].w + bv.w) * s;
            if (BF16OUT) {
                ushort4 p;
                p.x = f2bf(o.x); p.y = f2bf(o.y); p.z = f2bf(o.z); p.w = f2bf(o.w);
                ((ushort4*)Hout)[(size_t)r * 16 + (t & 15)] = p;
            } else {
                ((float4*)Hout)[(size_t)r * 16 + (t & 15)] = o;
            }
        }
    }
}

// Fused aggregation + next-layer GEMM, v2 (R10 post-mortem: the per-half-wave
// W^T sweep caused 1.14e7 LDS bank conflicts + 16 KB LDS W-traffic per row).
// Block = 32 nodes. Phase 1: 4 passes of the R9 gather (wave = 2 nodes, 16
// row-gathers in flight); relu'd rows -> LDS. ONE barrier. Phase 2: exact
// k_gemm pattern (k-major Ws, thread = 2 rows x 4 cols) — measured
// 0-conflict reads, W traffic amortized over 32 rows.
// MODE 0: emit bf16 dinv*(row@W) for next layer.
// MODE 1: emit out0 = relu row (graded) and out1 = row@Wl + bl (graded).
template <int MODE>
__global__ __launch_bounds__(256) void k_fused(const uint4* __restrict__ Hb,
                                               const int* __restrict__ noffs,
                                               const int* __restrict__ csr_src,
                                               const float* __restrict__ dinv,
                                               const float4* __restrict__ b4,
                                               const float* __restrict__ Wn,
                                               const float* __restrict__ bl,
                                               unsigned short* __restrict__ HbOut,
                                               float4* __restrict__ out0,
                                               float* __restrict__ out1) {
    __shared__ float Ws[64 * LDW];     // W, k-major (same as k_gemm), 17.4 KB
    __shared__ float rows[32 * LDW];   // 32 relu'd rows, 8.7 KB
    __shared__ float dvs[32];
    __shared__ float bls[64];
    int t = threadIdx.x;
    for (int i = t; i < 64 * 16; i += 256) {       // stage W (k-major, float4)
        float4 v = ((const float4*)Wn)[i];
        *(float4*)&Ws[(i >> 4) * LDW + (i & 15) * 4] = v;
    }
    if (MODE == 1 && t < 64) bls[t] = bl[t];

    // ---- phase 1: 4 gather passes (R9 structure: wave = 2 nodes) ----
    int lane = t & 63;
    int half = lane >> 5, hl = lane & 31;
    int c = hl >> 3, q = hl & 7;
    int base = blockIdx.x * 32;
#pragma unroll 1
    for (int p = 0; p < 4; ++p) {
        int nl = p * 8 + (t >> 6) * 2 + half;  // node slot 0..31
        int node = base + nl;
        float dv = 0.f;
        float4 alo = make_float4(0.f, 0.f, 0.f, 0.f);
        float4 ahi = make_float4(0.f, 0.f, 0.f, 0.f);
        if (node < NN) {
            dv = dinv[node];
            if (c == 0) {                      // self-loop (prescaled)
                uint4 u = Hb[(size_t)node * 8 + q];
                bfacc(u, alo, ahi);
            }
            int e0 = noffs[node], e1 = noffs[node + 1];
            int e = e0 + c;
            for (; e + 4 < e1; e += 8) {
                uint4 u0 = Hb[(size_t)csr_src[e] * 8 + q];
                uint4 u1 = Hb[(size_t)csr_src[e + 4] * 8 + q];
                bfacc(u0, alo, ahi);
                bfacc(u1, alo, ahi);
            }
            if (e < e1) {
                uint4 u = Hb[(size_t)csr_src[e] * 8 + q];
                bfacc(u, alo, ahi);
            }
        }
#pragma unroll
        for (int off = 8; off < 32; off <<= 1) {   // reduce 4 clusters/half
            alo.x += __shfl_xor(alo.x, off, 64);
            alo.y += __shfl_xor(alo.y, off, 64);
            alo.z += __shfl_xor(alo.z, off, 64);
            alo.w += __shfl_xor(alo.w, off, 64);
            ahi.x += __shfl_xor(ahi.x, off, 64);
            ahi.y += __shfl_xor(ahi.y, off, 64);
            ahi.z += __shfl_xor(ahi.z, off, 64);
            ahi.w += __shfl_xor(ahi.w, off, 64);
        }
        if (c == 0 && node < NN) {             // relu'd row -> LDS
            float4 b0v = b4[2 * q], b1v = b4[2 * q + 1];
            float4 r0, r1;
            r0.x = fmaxf(alo.x * dv + b0v.x, 0.f);
            r0.y = fmaxf(alo.y * dv + b0v.y, 0.f);
            r0.z = fmaxf(alo.z * dv + b0v.z, 0.f);
            r0.w = fmaxf(alo.w * dv + b0v.w, 0.f);
            r1.x = fmaxf(ahi.x * dv + b1v.x, 0.f);
            r1.y = fmaxf(ahi.y * dv + b1v.y, 0.f);
            r1.z = fmaxf(ahi.z * dv + b1v.z, 0.f);
            r1.w = fmaxf(ahi.w * dv + b1v.w, 0.f);
            *(float4*)&rows[nl * LDW + 8 * q]     = r0;
            *(float4*)&rows[nl * LDW + 8 * q + 4] = r1;
            if (MODE == 1) {
                out0[(size_t)node * 16 + 2 * q]     = r0;
                out0[(size_t)node * 16 + 2 * q + 1] = r1;
            }
            if (q == 0) dvs[nl] = dv;
        }
    }
    __syncthreads();                           // the only barrier

    // ---- phase 2: rows @ Ws, k_gemm pattern (2 rows x 4 cols / thread) ----
    int tc = (t & 15) * 4;
    int rbase = t >> 4;                        // rows rbase, rbase+16
    float4 a0 = make_float4(0.f, 0.f, 0.f, 0.f);
    float4 a1 = make_float4(0.f, 0.f, 0.f, 0.f);
#pragma unroll 1
    for (int k = 0; k < 64; k += 4) {
        float4 wv[4];
#pragma unroll
        for (int kk = 0; kk < 4; ++kk)
            wv[kk] = *(const float4*)&Ws[(k + kk) * LDW + tc];
        float4 x0 = *(const float4*)&rows[rbase * LDW + k];
        float4 x1 = *(const float4*)&rows[(rbase + 16) * LDW + k];
        a0.x += x0.x * wv[0].x + x0.y * wv[1].x + x0.z * wv[2].x + x0.w * wv[3].x;
        a0.y += x0.x * wv[0].y + x0.y * wv[1].y + x0.z * wv[2].y + x0.w * wv[3].y;
        a0.z += x0.x * wv[0].z + x0.y * wv[1].z + x0.z * wv[2].z + x0.w * wv[3].z;
        a0.w += x0.x * wv[0].w + x0.y * wv[1].w + x0.z * wv[2].w + x0.w * wv[3].w;
        a1.x += x1.x * wv[0].x + x1.y * wv[1].x + x1.z * wv[2].x + x1.w * wv[3].x;
        a1.y += x1.x * wv[0].y + x1.y * wv[1].y + x1.z * wv[2].y + x1.w * wv[3].y;
        a1.z += x1.x * wv[0].z + x1.y * wv[1].z + x1.z * wv[2].z + x1.w * wv[3].z;
        a1.w += x1.x * wv[0].w + x1.y * wv[1].w + x1.z * wv[2].w + x1.w * wv[3].w;
    }
    int n0 = base + rbase, n1 = base + rbase + 16;
    if (MODE == 0) {
        if (n0 < NN) {
            float s = dvs[rbase];
            ushort4 p;
            p.x = f2bf(a0.x * s); p.y = f2bf(a0.y * s);
            p.z = f2bf(a0.z * s); p.w = f2bf(a0.w * s);
            *(ushort4*)&HbOut[(size_t)n0 * 64 + tc] = p;
        }
        if (n1 < NN) {
            float s = dvs[rbase + 16];
            ushort4 p;
            p.x = f2bf(a1.x * s); p.y = f2bf(a1.y * s);
            p.z = f2bf(a1.z * s); p.w = f2bf(a1.w * s);
            *(ushort4*)&HbOut[(size_t)n1 * 64 + tc] = p;
        }
    } else {
        float4 bv = *(const float4*)&bls[tc];
        if (n0 < NN) {
            float4 o; o.x = a0.x + bv.x; o.y = a0.y + bv.y;
            o.z = a0.z + bv.z; o.w = a0.w + bv.w;
            *(float4*)&out1[(size_t)n0 * 64 + tc] = o;
        }
        if (n1 < NN) {
            float4 o; o.x = a1.x + bv.x; o.y = a1.y + bv.y;
            o.z = a1.z + bv.z; o.w = a1.w + bv.w;
            *(float4*)&out1[(size_t)n1 * 64 + tc] = o;
        }
    }
}

extern "C" void kernel_launch(void* const* d_in, const int* in_sizes, int n_in,
                              void* d_out, int out_size, void* d_ws, size_t ws_size,
                              hipStream_t stream) {
    const float* x  = (const float*)d_in[0];
    const void*  ei = d_in[1];               // edge_index, dtype detected on device
    const float* W0 = (const float*)d_in[3];
    const float* b0 = (const float*)d_in[4];
    const float* W1 = (const float*)d_in[5];
    const float* b1 = (const float*)d_in[6];
    const float* W2 = (const float*)d_in[7];
    const float* b2 = (const float*)d_in[8];
    const float* Wl = (const float*)d_in[9];
    const float* bl = (const float*)d_in[10];

    char* ws = (char*)d_ws;
    int*      flag    = (int*)(ws);
    int*      bcnt    = (int*)(ws + 256);
    int*      offs    = (int*)(ws + 4352);        // 783 ints
    int*      curs    = (int*)(ws + 8448);        // 782 ints
    float*    dinv    = (float*)(ws + 12544);     // 400000 B
    int*      noffs   = (int*)(ws + 412672);      // 100001 ints
    int*      csr_src = (int*)(ws + 812800);      // 3.2 MB
    unsigned short* HbA = (unsigned short*)(ws + 4100096);    // 12.8 MB
    unsigned short* HbB = (unsigned short*)(ws + 16900096);   // 12.8 MB

    float* out0 = (float*)d_out;             // graded relu output (h3)
    float* out1 = out0 + (size_t)NN * HD;    // graded linear output
    unsigned* ebuf = (unsigned*)out1;        // bucket-major edges; dies pre-GEMM0

    int gG = (NN + 127) / 128;               // 782 gemm blocks
    int gF = (NN + 31) / 32;                 // 3125 fused blocks (32 nodes each)

    // ---- preprocessing: bucket bin + in-bucket counting sort -> CSR ----
    k_initdet<<<1, 1024, 0, stream>>>(ei, bcnt, flag);
    k_pass0<<<128, 256, 0, stream>>>(ei, flag, bcnt);
    k_scan1<<<1, 256, 0, stream>>>(bcnt, offs, curs);
    k_passA<<<PA_NB, 256, 0, stream>>>(ei, flag, curs, ebuf);
    k_passB<<<NBUCK, 256, 0, stream>>>(ebuf, offs, noffs, csr_src, dinv);

    // ---- layer 0 GEMM: HbA = dinv * (x @ W0), bf16 ----
    k_gemm<false, true, true><<<gG, 256, 0, stream>>>(x, W0, nullptr, dinv,
                                                      (void*)HbA, NN);
    // ---- fused layer 1: agg(HbA)+b0+relu, @W1*dinv -> HbB ----
    k_fused<0><<<gF, 256, 0, stream>>>((const uint4*)HbA, noffs, csr_src, dinv,
                                       (const float4*)b0, W1, nullptr,
                                       HbB, nullptr, nullptr);
    // ---- fused layer 2: agg(HbB)+b1+relu, @W2*dinv -> HbA ----
    k_fused<0><<<gF, 256, 0, stream>>>((const uint4*)HbB, noffs, csr_src, dinv,
                                       (const float4*)b1, W2, nullptr,
                                       HbA, nullptr, nullptr);
    // ---- fused final: agg(HbA)+b2+relu -> out0 ; row@Wl+bl -> out1 ----
    k_fused<1><<<gF, 256, 0, stream>>>((const uint4*)HbA, noffs, csr_src, dinv,
                                       (const float4*)b2, Wl, bl,
                                       nullptr, (float4*)out0, out1);
}

// Round 12
// 268.979 us; speedup vs baseline: 1.1529x; 1.0720x over previous
//
#include <hip/hip_runtime.h>

#define NN 100000
#define NE 800000
#define HD 64
#define BK 128                            // nodes per bucket
#define NBUCK ((NN + BK - 1) / BK)        // 782
#define PA_EPT 16                         // edges per thread in passA
#define PA_NB ((NE + 256 * PA_EPT - 1) / (256 * PA_EPT))   // 196
#define LDW 68                            // padded leading dim: 68 f = 272 B

__device__ __forceinline__ int load_idx(const void* ei, int i, bool is32) {
    if (is32) return ((const int*)ei)[i];
    return (int)(((const long long*)ei)[i]);
}

__device__ __forceinline__ unsigned short f2bf(float f) {   // round-to-nearest
    unsigned u = __float_as_uint(f);
    return (unsigned short)((u + 0x7FFFu + ((u >> 16) & 1u)) >> 16);
}

// expand uint4 (8 packed bf16, feature order) and accumulate into 2 float4s
__device__ __forceinline__ void bfacc(const uint4& u, float4& a, float4& b) {
    a.x += __uint_as_float(u.x << 16);
    a.y += __uint_as_float(u.x & 0xFFFF0000u);
    a.z += __uint_as_float(u.y << 16);
    a.w += __uint_as_float(u.y & 0xFFFF0000u);
    b.x += __uint_as_float(u.z << 16);
    b.y += __uint_as_float(u.z & 0xFFFF0000u);
    b.z += __uint_as_float(u.w << 16);
    b.w += __uint_as_float(u.w & 0xFFFF0000u);
}

// zero bucket counters + flag, then dtype-detect (int32 vs int64) in one launch.
__global__ void k_initdet(const void* ei, int* bcnt, int* flag) {
    __shared__ int bad;
    int t = threadIdx.x;
    if (t == 0) bad = 0;
    if (t < NBUCK) bcnt[t] = 0;
    __syncthreads();
    const long long* p = (const long long*)ei;
    for (int i = t; i < 4096; i += 1024) {
        long long v = p[i];
        if (v < 0 || v >= (long long)NN) bad = 1;
    }
    __syncthreads();
    if (t == 0) *flag = bad ? 1 : 0;
}

// global bucket histogram via per-block LDS histograms
__global__ __launch_bounds__(256) void k_pass0(const void* ei, const int* flag,
                                               int* bcnt) {
    __shared__ int h[NBUCK];
    for (int i = threadIdx.x; i < NBUCK; i += 256) h[i] = 0;
    __syncthreads();
    bool is32 = (*flag != 0);
    int stride = gridDim.x * 256;
    for (int e = blockIdx.x * 256 + threadIdx.x; e < NE; e += stride) {
        int dst = load_idx(ei, NE + e, is32);
        atomicAdd(&h[dst >> 7], 1);
    }
    __syncthreads();
    for (int i = threadIdx.x; i < NBUCK; i += 256) {
        int v = h[i];
        if (v) atomicAdd(&bcnt[i], v);
    }
}

// scan 782 bucket counts -> offs[0..NBUCK], curs[b]=offs[b]
__global__ __launch_bounds__(256) void k_scan1(const int* __restrict__ bcnt,
                                               int* __restrict__ offs,
                                               int* __restrict__ curs) {
    __shared__ int sc[256];
    int t = threadIdx.x;
    int v[4], s = 0;
#pragma unroll
    for (int i = 0; i < 4; ++i) {
        int b = t * 4 + i;
        v[i] = (b < NBUCK) ? bcnt[b] : 0;
        s += v[i];
    }
    sc[t] = s;
    __syncthreads();
    for (int off = 1; off < 256; off <<= 1) {
        int add = (t >= off) ? sc[t - off] : 0;
        __syncthreads();
        sc[t] += add;
        __syncthreads();
    }
    int run = sc[t] - s;   // exclusive prefix
#pragma unroll
    for (int i = 0; i < 4; ++i) {
        int b = t * 4 + i;
        if (b < NBUCK) { offs[b] = run; curs[b] = run; }
        run += v[i];
    }
    if (t == 255) offs[NBUCK] = sc[255];
}

// bin edges into bucket-major ebuf; packed word = src | (dst&127)<<17
__global__ __launch_bounds__(256) void k_passA(const void* ei, const int* flag,
                                               int* curs, unsigned* ebuf) {
    __shared__ int h[NBUCK];
    __shared__ int base[NBUCK];
    for (int i = threadIdx.x; i < NBUCK; i += 256) h[i] = 0;
    __syncthreads();
    bool is32 = (*flag != 0);
    int e0 = blockIdx.x * (256 * PA_EPT);
    int src[PA_EPT], dst[PA_EPT];
#pragma unroll
    for (int i = 0; i < PA_EPT; ++i) {
        int e = e0 + i * 256 + threadIdx.x;
        if (e < NE) {
            src[i] = load_idx(ei, e, is32);
            dst[i] = load_idx(ei, NE + e, is32);
            atomicAdd(&h[dst[i] >> 7], 1);
        } else dst[i] = -1;
    }
    __syncthreads();
    for (int i = threadIdx.x; i < NBUCK; i += 256) {
        int v = h[i];
        base[i] = v ? atomicAdd(&curs[i], v) : 0;
        h[i] = 0;                      // reuse as local rank counter
    }
    __syncthreads();
#pragma unroll
    for (int i = 0; i < PA_EPT; ++i) {
        if (dst[i] >= 0) {
            int b = dst[i] >> 7;
            int p = base[b] + atomicAdd(&h[b], 1);
            ebuf[p] = (unsigned)src[i] | ((unsigned)(dst[i] & 127) << 17);
        }
    }
}

// per-bucket counting sort -> per-node CSR (noffs, csr_src) + dinv.
__global__ __launch_bounds__(256) void k_passB(const unsigned* __restrict__ ebuf,
                                               const int* __restrict__ offs,
                                               int* __restrict__ noffs,
                                               int* __restrict__ csr_src,
                                               float* __restrict__ dinv) {
    __shared__ int cnt[BK];
    __shared__ int sc[BK];
    __shared__ int nbase[BK];
    __shared__ int rank[BK];
    int bk = blockIdx.x;
    int t = threadIdx.x;
    if (t < BK) { cnt[t] = 0; rank[t] = 0; }
    __syncthreads();
    int rs = offs[bk], re = offs[bk + 1];
    for (int i = rs + t; i < re; i += 256)
        atomicAdd(&cnt[ebuf[i] >> 17], 1);
    __syncthreads();
    if (t < BK) sc[t] = cnt[t];
    __syncthreads();
    for (int off = 1; off < BK; off <<= 1) {       // inclusive scan of cnt
        int v = 0;
        if (t < BK && t >= off) v = sc[t - off];
        __syncthreads();
        if (t < BK) sc[t] += v;
        __syncthreads();
    }
    if (t < BK) {
        int node = bk * BK + t;
        int nb = rs + sc[t] - cnt[t];              // exclusive prefix
        nbase[t] = nb;
        if (node < NN) {
            noffs[node] = nb;
            dinv[node] = rsqrtf((float)(cnt[t] + 1));
        }
    }
    if (bk == NBUCK - 1 && t == 0) noffs[NN] = re;
    __syncthreads();
    for (int i = rs + t; i < re; i += 256) {
        unsigned w = ebuf[i];
        int dl = w >> 17;
        int p = nbase[dl] + atomicAdd(&rank[dl], 1);
        csr_src[p] = (int)(w & 0x1FFFFu);
    }
}

// H = dinv * (X @ W) as bf16 rows (layer-0 only). 128 rows/block; thread =
// 8 rows (strided by 16) x 4 cols; unroll 1 + launch_bounds(256,4) (R6
// lesson: full unroll -> 256 VGPR, occupancy collapse).
template <bool BIAS, bool PRE, bool BF16OUT>
__global__ __launch_bounds__(256, 4) void k_gemm(const float* __restrict__ X,
                                                 const float* __restrict__ W,
                                                 const float* __restrict__ bias,
                                                 const float* __restrict__ dinv,
                                                 void* __restrict__ Hout, int n) {
    __shared__ float Ws[64 * LDW];     // 17.4 KB
    __shared__ float Xs[128 * LDW];    // 34.8 KB
    int t = threadIdx.x;
    int row0 = blockIdx.x * 128;
    const float4* X4 = (const float4*)X;
    for (int i = t; i < 64 * 16; i += 256) {       // W: 1024 float4
        float4 v = ((const float4*)W)[i];
        *(float4*)&Ws[(i >> 4) * LDW + (i & 15) * 4] = v;
    }
    for (int i = t; i < 128 * 16; i += 256) {      // X tile: 2048 float4
        int r = row0 + (i >> 4);
        float4 v = (r < n) ? X4[(size_t)r * 16 + (i & 15)]
                           : make_float4(0.f, 0.f, 0.f, 0.f);
        *(float4*)&Xs[(i >> 4) * LDW + (i & 15) * 4] = v;
    }
    __syncthreads();
    int tc = (t & 15) * 4;       // 4 output cols
    int rbase = t >> 4;          // rows rbase + 16*i, i=0..7
    float4 acc[8] = {};
#pragma unroll 1
    for (int k = 0; k < 64; k += 4) {
        float4 wv[4], xv[8];
#pragma unroll
        for (int kk = 0; kk < 4; ++kk)
            wv[kk] = *(const float4*)&Ws[(k + kk) * LDW + tc];
#pragma unroll
        for (int i = 0; i < 8; ++i)
            xv[i] = *(const float4*)&Xs[(rbase + 16 * i) * LDW + k];
#pragma unroll
        for (int i = 0; i < 8; ++i) {
            acc[i].x += xv[i].x * wv[0].x + xv[i].y * wv[1].x
                      + xv[i].z * wv[2].x + xv[i].w * wv[3].x;
            acc[i].y += xv[i].x * wv[0].y + xv[i].y * wv[1].y
                      + xv[i].z * wv[2].y + xv[i].w * wv[3].y;
            acc[i].z += xv[i].x * wv[0].z + xv[i].y * wv[1].z
                      + xv[i].z * wv[2].z + xv[i].w * wv[3].z;
            acc[i].w += xv[i].x * wv[0].w + xv[i].y * wv[1].w
                      + xv[i].z * wv[2].w + xv[i].w * wv[3].w;
        }
    }
    float4 bv = make_float4(0.f, 0.f, 0.f, 0.f);
    if (BIAS) bv = *(const float4*)&bias[tc];
#pragma unroll
    for (int i = 0; i < 8; ++i) {
        int r = row0 + rbase + 16 * i;
        if (r < n) {
            float s = PRE ? dinv[r] : 1.f;
            float4 o;
            o.x = (acc[i].x + bv.x) * s;
            o.y = (acc[i].y + bv.y) * s;
            o.z = (acc[i].z + bv.z) * s;
            o.w = (acc[i].w + bv.w) * s;
            if (BF16OUT) {
                ushort4 p;
                p.x = f2bf(o.x); p.y = f2bf(o.y); p.z = f2bf(o.z); p.w = f2bf(o.w);
                ((ushort4*)Hout)[(size_t)r * 16 + (t & 15)] = p;
            } else {
                ((float4*)Hout)[(size_t)r * 16 + (t & 15)] = o;
            }
        }
    }
}

// Fused aggregation + next-layer GEMM, v3. Phase 1 MLP upgrade (R11 post-
// mortem: still gather-latency-bound): wave = 4 nodes, each node = 2 clusters
// of 8 lanes, cluster walks its node's edges stride-2 with 4-deep unroll ->
// 32 independent row-gathers in flight per wave (R11 had 16). 4-deep matches
// mean degree 8 (4 edges/cluster). Reduction = one shfl_xor(8) set.
// Phase 2 unchanged: k_gemm pattern (k-major Ws), measured ~0 conflicts.
// MODE 0: emit bf16 dinv*(row@W) for next layer.
// MODE 1: emit out0 = relu row (graded) and out1 = row@Wl + bl (graded).
template <int MODE>
__global__ __launch_bounds__(256) void k_fused(const uint4* __restrict__ Hb,
                                               const int* __restrict__ noffs,
                                               const int* __restrict__ csr_src,
                                               const float* __restrict__ dinv,
                                               const float4* __restrict__ b4,
                                               const float* __restrict__ Wn,
                                               const float* __restrict__ bl,
                                               unsigned short* __restrict__ HbOut,
                                               float4* __restrict__ out0,
                                               float* __restrict__ out1) {
    __shared__ float Ws[64 * LDW];     // W, k-major (same as k_gemm), 17.4 KB
    __shared__ float rows[32 * LDW];   // 32 relu'd rows, 8.7 KB
    __shared__ float dvs[32];
    __shared__ float bls[64];
    int t = threadIdx.x;
    for (int i = t; i < 64 * 16; i += 256) {       // stage W (k-major, float4)
        float4 v = ((const float4*)Wn)[i];
        *(float4*)&Ws[(i >> 4) * LDW + (i & 15) * 4] = v;
    }
    if (MODE == 1 && t < 64) bls[t] = bl[t];

    // ---- phase 1: 2 gather passes; wave = 4 nodes x 2 clusters x 4-deep ----
    int lane = t & 63;
    int nq = lane >> 4;                        // node within wave 0..3
    int hl = lane & 15;
    int c = hl >> 3;                           // cluster 0..1
    int q = hl & 7;                            // uint4 chunk 0..7
    int base = blockIdx.x * 32;
#pragma unroll 1
    for (int p = 0; p < 2; ++p) {
        int nl = p * 16 + (t >> 6) * 4 + nq;   // node slot 0..31
        int node = base + nl;
        float dv = 0.f;
        float4 alo = make_float4(0.f, 0.f, 0.f, 0.f);
        float4 ahi = make_float4(0.f, 0.f, 0.f, 0.f);
        if (node < NN) {
            dv = dinv[node];
            if (c == 0) {                      // self-loop (prescaled)
                uint4 u = Hb[(size_t)node * 8 + q];
                bfacc(u, alo, ahi);
            }
            int e0 = noffs[node], e1 = noffs[node + 1];
            int e = e0 + c;
            for (; e + 6 < e1; e += 8) {       // 4 indices then 4 gathers
                int s0 = csr_src[e],     s1 = csr_src[e + 2];
                int s2 = csr_src[e + 4], s3 = csr_src[e + 6];
                uint4 u0 = Hb[(size_t)s0 * 8 + q];
                uint4 u1 = Hb[(size_t)s1 * 8 + q];
                uint4 u2 = Hb[(size_t)s2 * 8 + q];
                uint4 u3 = Hb[(size_t)s3 * 8 + q];
                bfacc(u0, alo, ahi);
                bfacc(u1, alo, ahi);
                bfacc(u2, alo, ahi);
                bfacc(u3, alo, ahi);
            }
            for (; e < e1; e += 2) {
                uint4 u = Hb[(size_t)csr_src[e] * 8 + q];
                bfacc(u, alo, ahi);
            }
        }
        // reduce the 2 clusters (lanes q and q+8 within each 16-lane group)
        alo.x += __shfl_xor(alo.x, 8, 64);
        alo.y += __shfl_xor(alo.y, 8, 64);
        alo.z += __shfl_xor(alo.z, 8, 64);
        alo.w += __shfl_xor(alo.w, 8, 64);
        ahi.x += __shfl_xor(ahi.x, 8, 64);
        ahi.y += __shfl_xor(ahi.y, 8, 64);
        ahi.z += __shfl_xor(ahi.z, 8, 64);
        ahi.w += __shfl_xor(ahi.w, 8, 64);
        if (c == 0 && node < NN) {             // relu'd row -> LDS
            float4 b0v = b4[2 * q], b1v = b4[2 * q + 1];
            float4 r0, r1;
            r0.x = fmaxf(alo.x * dv + b0v.x, 0.f);
            r0.y = fmaxf(alo.y * dv + b0v.y, 0.f);
            r0.z = fmaxf(alo.z * dv + b0v.z, 0.f);
            r0.w = fmaxf(alo.w * dv + b0v.w, 0.f);
            r1.x = fmaxf(ahi.x * dv + b1v.x, 0.f);
            r1.y = fmaxf(ahi.y * dv + b1v.y, 0.f);
            r1.z = fmaxf(ahi.z * dv + b1v.z, 0.f);
            r1.w = fmaxf(ahi.w * dv + b1v.w, 0.f);
            *(float4*)&rows[nl * LDW + 8 * q]     = r0;
            *(float4*)&rows[nl * LDW + 8 * q + 4] = r1;
            if (MODE == 1) {
                out0[(size_t)node * 16 + 2 * q]     = r0;
                out0[(size_t)node * 16 + 2 * q + 1] = r1;
            }
            if (q == 0) dvs[nl] = dv;
        }
    }
    __syncthreads();                           // the only barrier

    // ---- phase 2: rows @ Ws, k_gemm pattern (2 rows x 4 cols / thread) ----
    int tc = (t & 15) * 4;
    int rbase = t >> 4;                        // rows rbase, rbase+16
    float4 a0 = make_float4(0.f, 0.f, 0.f, 0.f);
    float4 a1 = make_float4(0.f, 0.f, 0.f, 0.f);
#pragma unroll 1
    for (int k = 0; k < 64; k += 4) {
        float4 wv[4];
#pragma unroll
        for (int kk = 0; kk < 4; ++kk)
            wv[kk] = *(const float4*)&Ws[(k + kk) * LDW + tc];
        float4 x0 = *(const float4*)&rows[rbase * LDW + k];
        float4 x1 = *(const float4*)&rows[(rbase + 16) * LDW + k];
        a0.x += x0.x * wv[0].x + x0.y * wv[1].x + x0.z * wv[2].x + x0.w * wv[3].x;
        a0.y += x0.x * wv[0].y + x0.y * wv[1].y + x0.z * wv[2].y + x0.w * wv[3].y;
        a0.z += x0.x * wv[0].z + x0.y * wv[1].z + x0.z * wv[2].z + x0.w * wv[3].z;
        a0.w += x0.x * wv[0].w + x0.y * wv[1].w + x0.z * wv[2].w + x0.w * wv[3].w;
        a1.x += x1.x * wv[0].x + x1.y * wv[1].x + x1.z * wv[2].x + x1.w * wv[3].x;
        a1.y += x1.x * wv[0].y + x1.y * wv[1].y + x1.z * wv[2].y + x1.w * wv[3].y;
        a1.z += x1.x * wv[0].z + x1.y * wv[1].z + x1.z * wv[2].z + x1.w * wv[3].z;
        a1.w += x1.x * wv[0].w + x1.y * wv[1].w + x1.z * wv[2].w + x1.w * wv[3].w;
    }
    int n0 = base + rbase, n1 = base + rbase + 16;
    if (MODE == 0) {
        if (n0 < NN) {
            float s = dvs[rbase];
            ushort4 p;
            p.x = f2bf(a0.x * s); p.y = f2bf(a0.y * s);
            p.z = f2bf(a0.z * s); p.w = f2bf(a0.w * s);
            *(ushort4*)&HbOut[(size_t)n0 * 64 + tc] = p;
        }
        if (n1 < NN) {
            float s = dvs[rbase + 16];
            ushort4 p;
            p.x = f2bf(a1.x * s); p.y = f2bf(a1.y * s);
            p.z = f2bf(a1.z * s); p.w = f2bf(a1.w * s);
            *(ushort4*)&HbOut[(size_t)n1 * 64 + tc] = p;
        }
    } else {
        float4 bv = *(const float4*)&bls[tc];
        if (n0 < NN) {
            float4 o; o.x = a0.x + bv.x; o.y = a0.y + bv.y;
            o.z = a0.z + bv.z; o.w = a0.w + bv.w;
            *(float4*)&out1[(size_t)n0 * 64 + tc] = o;
        }
        if (n1 < NN) {
            float4 o; o.x = a1.x + bv.x; o.y = a1.y + bv.y;
            o.z = a1.z + bv.z; o.w = a1.w + bv.w;
            *(float4*)&out1[(size_t)n1 * 64 + tc] = o;
        }
    }
}

extern "C" void kernel_launch(void* const* d_in, const int* in_sizes, int n_in,
                              void* d_out, int out_size, void* d_ws, size_t ws_size,
                              hipStream_t stream) {
    const float* x  = (const float*)d_in[0];
    const void*  ei = d_in[1];               // edge_index, dtype detected on device
    const float* W0 = (const float*)d_in[3];
    const float* b0 = (const float*)d_in[4];
    const float* W1 = (const float*)d_in[5];
    const float* b1 = (const float*)d_in[6];
    const float* W2 = (const float*)d_in[7];
    const float* b2 = (const float*)d_in[8];
    const float* Wl = (const float*)d_in[9];
    const float* bl = (const float*)d_in[10];

    char* ws = (char*)d_ws;
    int*      flag    = (int*)(ws);
    int*      bcnt    = (int*)(ws + 256);
    int*      offs    = (int*)(ws + 4352);        // 783 ints
    int*      curs    = (int*)(ws + 8448);        // 782 ints
    float*    dinv    = (float*)(ws + 12544);     // 400000 B
    int*      noffs   = (int*)(ws + 412672);      // 100001 ints
    int*      csr_src = (int*)(ws + 812800);      // 3.2 MB
    unsigned short* HbA = (unsigned short*)(ws + 4100096);    // 12.8 MB
    unsigned short* HbB = (unsigned short*)(ws + 16900096);   // 12.8 MB

    float* out0 = (float*)d_out;             // graded relu output (h3)
    float* out1 = out0 + (size_t)NN * HD;    // graded linear output
    unsigned* ebuf = (unsigned*)out1;        // bucket-major edges; dies pre-GEMM0

    int gG = (NN + 127) / 128;               // 782 gemm blocks
    int gF = (NN + 31) / 32;                 // 3125 fused blocks (32 nodes each)

    // ---- preprocessing: bucket bin + in-bucket counting sort -> CSR ----
    k_initdet<<<1, 1024, 0, stream>>>(ei, bcnt, flag);
    k_pass0<<<128, 256, 0, stream>>>(ei, flag, bcnt);
    k_scan1<<<1, 256, 0, stream>>>(bcnt, offs, curs);
    k_passA<<<PA_NB, 256, 0, stream>>>(ei, flag, curs, ebuf);
    k_passB<<<NBUCK, 256, 0, stream>>>(ebuf, offs, noffs, csr_src, dinv);

    // ---- layer 0 GEMM: HbA = dinv * (x @ W0), bf16 ----
    k_gemm<false, true, true><<<gG, 256, 0, stream>>>(x, W0, nullptr, dinv,
                                                      (void*)HbA, NN);
    // ---- fused layer 1: agg(HbA)+b0+relu, @W1*dinv -> HbB ----
    k_fused<0><<<gF, 256, 0, stream>>>((const uint4*)HbA, noffs, csr_src, dinv,
                                       (const float4*)b0, W1, nullptr,
                                       HbB, nullptr, nullptr);
    // ---- fused layer 2: agg(HbB)+b1+relu, @W2*dinv -> HbA ----
    k_fused<0><<<gF, 256, 0, stream>>>((const uint4*)HbB, noffs, csr_src, dinv,
                                       (const float4*)b1, W2, nullptr,
                                       HbA, nullptr, nullptr);
    // ---- fused final: agg(HbA)+b2+relu -> out0 ; row@Wl+bl -> out1 ----
    k_fused<1><<<gF, 256, 0, stream>>>((const uint4*)HbA, noffs, csr_src, dinv,
                                       (const float4*)b2, Wl, bl,
                                       nullptr, (float4*)out0, out1);
}

// Round 13
// 241.200 us; speedup vs baseline: 1.2857x; 1.1152x over previous
//
#include <hip/hip_runtime.h>

#define NN 100000
#define NE 800000
#define HD 64
#define BK 128                            // nodes per bucket
#define NBUCK ((NN + BK - 1) / BK)        // 782
#define PA_EPT 16                         // edges per thread in passA
#define PA_NB ((NE + 256 * PA_EPT - 1) / (256 * PA_EPT))   // 196
#define LDW 68                            // padded leading dim: 68 f = 272 B

__device__ __forceinline__ int load_idx(const void* ei, int i, bool is32) {
    if (is32) return ((const int*)ei)[i];
    return (int)(((const long long*)ei)[i]);
}

__device__ __forceinline__ unsigned short f2bf(float f) {   // round-to-nearest
    unsigned u = __float_as_uint(f);
    return (unsigned short)((u + 0x7FFFu + ((u >> 16) & 1u)) >> 16);
}

// expand uint4 (8 packed bf16, feature order) and accumulate into 2 float4s
__device__ __forceinline__ void bfacc(const uint4& u, float4& a, float4& b) {
    a.x += __uint_as_float(u.x << 16);
    a.y += __uint_as_float(u.x & 0xFFFF0000u);
    a.z += __uint_as_float(u.y << 16);
    a.w += __uint_as_float(u.y & 0xFFFF0000u);
    b.x += __uint_as_float(u.z << 16);
    b.y += __uint_as_float(u.z & 0xFFFF0000u);
    b.z += __uint_as_float(u.w << 16);
    b.w += __uint_as_float(u.w & 0xFFFF0000u);
}

// zero bucket counters + flag, then dtype-detect (int32 vs int64) in one launch.
__global__ void k_initdet(const void* ei, int* bcnt, int* flag) {
    __shared__ int bad;
    int t = threadIdx.x;
    if (t == 0) bad = 0;
    if (t < NBUCK) bcnt[t] = 0;
    __syncthreads();
    const long long* p = (const long long*)ei;
    for (int i = t; i < 4096; i += 1024) {
        long long v = p[i];
        if (v < 0 || v >= (long long)NN) bad = 1;
    }
    __syncthreads();
    if (t == 0) *flag = bad ? 1 : 0;
}

// global bucket histogram via per-block LDS histograms
__global__ __launch_bounds__(256) void k_pass0(const void* ei, const int* flag,
                                               int* bcnt) {
    __shared__ int h[NBUCK];
    for (int i = threadIdx.x; i < NBUCK; i += 256) h[i] = 0;
    __syncthreads();
    bool is32 = (*flag != 0);
    int stride = gridDim.x * 256;
    for (int e = blockIdx.x * 256 + threadIdx.x; e < NE; e += stride) {
        int dst = load_idx(ei, NE + e, is32);
        atomicAdd(&h[dst >> 7], 1);
    }
    __syncthreads();
    for (int i = threadIdx.x; i < NBUCK; i += 256) {
        int v = h[i];
        if (v) atomicAdd(&bcnt[i], v);
    }
}

// scan 782 bucket counts -> offs[0..NBUCK], curs[b]=offs[b]
__global__ __launch_bounds__(256) void k_scan1(const int* __restrict__ bcnt,
                                               int* __restrict__ offs,
                                               int* __restrict__ curs) {
    __shared__ int sc[256];
    int t = threadIdx.x;
    int v[4], s = 0;
#pragma unroll
    for (int i = 0; i < 4; ++i) {
        int b = t * 4 + i;
        v[i] = (b < NBUCK) ? bcnt[b] : 0;
        s += v[i];
    }
    sc[t] = s;
    __syncthreads();
    for (int off = 1; off < 256; off <<= 1) {
        int add = (t >= off) ? sc[t - off] : 0;
        __syncthreads();
        sc[t] += add;
        __syncthreads();
    }
    int run = sc[t] - s;   // exclusive prefix
#pragma unroll
    for (int i = 0; i < 4; ++i) {
        int b = t * 4 + i;
        if (b < NBUCK) { offs[b] = run; curs[b] = run; }
        run += v[i];
    }
    if (t == 255) offs[NBUCK] = sc[255];
}

// bin edges into bucket-major ebuf; packed word = src | (dst&127)<<17
__global__ __launch_bounds__(256) void k_passA(const void* ei, const int* flag,
                                               int* curs, unsigned* ebuf) {
    __shared__ int h[NBUCK];
    __shared__ int base[NBUCK];
    for (int i = threadIdx.x; i < NBUCK; i += 256) h[i] = 0;
    __syncthreads();
    bool is32 = (*flag != 0);
    int e0 = blockIdx.x * (256 * PA_EPT);
    int src[PA_EPT], dst[PA_EPT];
#pragma unroll
    for (int i = 0; i < PA_EPT; ++i) {
        int e = e0 + i * 256 + threadIdx.x;
        if (e < NE) {
            src[i] = load_idx(ei, e, is32);
            dst[i] = load_idx(ei, NE + e, is32);
            atomicAdd(&h[dst[i] >> 7], 1);
        } else dst[i] = -1;
    }
    __syncthreads();
    for (int i = threadIdx.x; i < NBUCK; i += 256) {
        int v = h[i];
        base[i] = v ? atomicAdd(&curs[i], v) : 0;
        h[i] = 0;                      // reuse as local rank counter
    }
    __syncthreads();
#pragma unroll
    for (int i = 0; i < PA_EPT; ++i) {
        if (dst[i] >= 0) {
            int b = dst[i] >> 7;
            int p = base[b] + atomicAdd(&h[b], 1);
            ebuf[p] = (unsigned)src[i] | ((unsigned)(dst[i] & 127) << 17);
        }
    }
}

// per-bucket counting sort -> per-node CSR (noffs, csr_src) + dinv.
__global__ __launch_bounds__(256) void k_passB(const unsigned* __restrict__ ebuf,
                                               const int* __restrict__ offs,
                                               int* __restrict__ noffs,
                                               int* __restrict__ csr_src,
                                               float* __restrict__ dinv) {
    __shared__ int cnt[BK];
    __shared__ int sc[BK];
    __shared__ int nbase[BK];
    __shared__ int rank[BK];
    int bk = blockIdx.x;
    int t = threadIdx.x;
    if (t < BK) { cnt[t] = 0; rank[t] = 0; }
    __syncthreads();
    int rs = offs[bk], re = offs[bk + 1];
    for (int i = rs + t; i < re; i += 256)
        atomicAdd(&cnt[ebuf[i] >> 17], 1);
    __syncthreads();
    if (t < BK) sc[t] = cnt[t];
    __syncthreads();
    for (int off = 1; off < BK; off <<= 1) {       // inclusive scan of cnt
        int v = 0;
        if (t < BK && t >= off) v = sc[t - off];
        __syncthreads();
        if (t < BK) sc[t] += v;
        __syncthreads();
    }
    if (t < BK) {
        int node = bk * BK + t;
        int nb = rs + sc[t] - cnt[t];              // exclusive prefix
        nbase[t] = nb;
        if (node < NN) {
            noffs[node] = nb;
            dinv[node] = rsqrtf((float)(cnt[t] + 1));
        }
    }
    if (bk == NBUCK - 1 && t == 0) noffs[NN] = re;
    __syncthreads();
    for (int i = rs + t; i < re; i += 256) {
        unsigned w = ebuf[i];
        int dl = w >> 17;
        int p = nbase[dl] + atomicAdd(&rank[dl], 1);
        csr_src[p] = (int)(w & 0x1FFFFu);
    }
}

// H = dinv * (X @ W) as bf16 rows (layer-0 only). 128 rows/block; thread =
// 8 rows (strided by 16) x 4 cols; unroll 1 + launch_bounds(256,4) (R6
// lesson: full unroll -> 256 VGPR, occupancy collapse).
template <bool BIAS, bool PRE, bool BF16OUT>
__global__ __launch_bounds__(256, 4) void k_gemm(const float* __restrict__ X,
                                                 const float* __restrict__ W,
                                                 const float* __restrict__ bias,
                                                 const float* __restrict__ dinv,
                                                 void* __restrict__ Hout, int n) {
    __shared__ float Ws[64 * LDW];     // 17.4 KB
    __shared__ float Xs[128 * LDW];    // 34.8 KB
    int t = threadIdx.x;
    int row0 = blockIdx.x * 128;
    const float4* X4 = (const float4*)X;
    for (int i = t; i < 64 * 16; i += 256) {       // W: 1024 float4
        float4 v = ((const float4*)W)[i];
        *(float4*)&Ws[(i >> 4) * LDW + (i & 15) * 4] = v;
    }
    for (int i = t; i < 128 * 16; i += 256) {      // X tile: 2048 float4
        int r = row0 + (i >> 4);
        float4 v = (r < n) ? X4[(size_t)r * 16 + (i & 15)]
                           : make_float4(0.f, 0.f, 0.f, 0.f);
        *(float4*)&Xs[(i >> 4) * LDW + (i & 15) * 4] = v;
    }
    __syncthreads();
    int tc = (t & 15) * 4;       // 4 output cols
    int rbase = t >> 4;          // rows rbase + 16*i, i=0..7
    float4 acc[8] = {};
#pragma unroll 1
    for (int k = 0; k < 64; k += 4) {
        float4 wv[4], xv[8];
#pragma unroll
        for (int kk = 0; kk < 4; ++kk)
            wv[kk] = *(const float4*)&Ws[(k + kk) * LDW + tc];
#pragma unroll
        for (int i = 0; i < 8; ++i)
            xv[i] = *(const float4*)&Xs[(rbase + 16 * i) * LDW + k];
#pragma unroll
        for (int i = 0; i < 8; ++i) {
            acc[i].x += xv[i].x * wv[0].x + xv[i].y * wv[1].x
                      + xv[i].z * wv[2].x + xv[i].w * wv[3].x;
            acc[i].y += xv[i].x * wv[0].y + xv[i].y * wv[1].y
                      + xv[i].z * wv[2].y + xv[i].w * wv[3].y;
            acc[i].z += xv[i].x * wv[0].z + xv[i].y * wv[1].z
                      + xv[i].z * wv[2].z + xv[i].w * wv[3].z;
            acc[i].w += xv[i].x * wv[0].w + xv[i].y * wv[1].w
                      + xv[i].z * wv[2].w + xv[i].w * wv[3].w;
        }
    }
    float4 bv = make_float4(0.f, 0.f, 0.f, 0.f);
    if (BIAS) bv = *(const float4*)&bias[tc];
#pragma unroll
    for (int i = 0; i < 8; ++i) {
        int r = row0 + rbase + 16 * i;
        if (r < n) {
            float s = PRE ? dinv[r] : 1.f;
            float4 o;
            o.x = (acc[i].x + bv.x) * s;
            o.y = (acc[i].y + bv.y) * s;
            o.z = (acc[i].z + bv.z) * s;
            o.w = (acc[i].w + bv.w) * s;
            if (BF16OUT) {
                ushort4 p;
                p.x = f2bf(o.x); p.y = f2bf(o.y); p.z = f2bf(o.z); p.w = f2bf(o.w);
                ((ushort4*)Hout)[(size_t)r * 16 + (t & 15)] = p;
            } else {
                ((float4*)Hout)[(size_t)r * 16 + (t & 15)] = o;
            }
        }
    }
}

// Fused aggregation + next-layer GEMM, v4. Phase 1 (R12 post-mortem: still
// gather-latency-bound): wave = 8 nodes, ONE 8-lane cluster per node owning
// all its edges, 8-deep unroll -> 64 independent row-gathers in flight per
// wave (R12: 32). 8-deep matches mean degree 8 (one iteration typical); no
// cross-cluster shfl reduce needed (each lane owns its 8 features). Indices:
// lane q loads csr_src[e+q] coalesced, broadcast via 8 bpermutes; j >= rem
// clamps to row 0 with predicated accumulate (straight-line, loads batched).
// Phase 2 unchanged: k_gemm pattern (k-major Ws), measured ~0 conflicts.
// MODE 0: emit bf16 dinv*(row@W) for next layer.
// MODE 1: emit out0 = relu row (graded) and out1 = row@Wl + bl (graded).
template <int MODE>
__global__ __launch_bounds__(256, 4) void k_fused(const uint4* __restrict__ Hb,
                                               const int* __restrict__ noffs,
                                               const int* __restrict__ csr_src,
                                               const float* __restrict__ dinv,
                                               const float4* __restrict__ b4,
                                               const float* __restrict__ Wn,
                                               const float* __restrict__ bl,
                                               unsigned short* __restrict__ HbOut,
                                               float4* __restrict__ out0,
                                               float* __restrict__ out1) {
    __shared__ float Ws[64 * LDW];     // W, k-major (same as k_gemm), 17.4 KB
    __shared__ float rows[32 * LDW];   // 32 relu'd rows, 8.7 KB
    __shared__ float dvs[32];
    __shared__ float bls[64];
    int t = threadIdx.x;
    for (int i = t; i < 64 * 16; i += 256) {       // stage W (k-major, float4)
        float4 v = ((const float4*)Wn)[i];
        *(float4*)&Ws[(i >> 4) * LDW + (i & 15) * 4] = v;
    }
    if (MODE == 1 && t < 64) bls[t] = bl[t];

    // ---- phase 1: one pass; wave = 8 nodes x 8-lane cluster x 8-deep ----
    int lane = t & 63;
    int cl = lane >> 3;                        // cluster (node) within wave 0..7
    int q = lane & 7;                          // uint4 chunk 0..7
    int cbase = lane & ~7;                     // cluster base lane (for shfl)
    int nl = (t >> 6) * 8 + cl;                // node slot 0..31
    int base = blockIdx.x * 32;
    int node = base + nl;
    float dv = 0.f;
    float4 alo = make_float4(0.f, 0.f, 0.f, 0.f);
    float4 ahi = make_float4(0.f, 0.f, 0.f, 0.f);
    if (node < NN) {
        dv = dinv[node];
        {                                       // self-loop (prescaled)
            uint4 u = Hb[(size_t)node * 8 + q];
            bfacc(u, alo, ahi);
        }
        int e0 = noffs[node], e1 = noffs[node + 1];
#pragma unroll 1
        for (int e = e0; e < e1; e += 8) {
            int rem = e1 - e;                   // >= 1
            int idx = (q < rem) ? csr_src[e + q] : 0;
            int s[8];
#pragma unroll
            for (int j = 0; j < 8; ++j)
                s[j] = __shfl(idx, cbase + j, 64);
            uint4 uu[8];
#pragma unroll
            for (int j = 0; j < 8; ++j)
                uu[j] = Hb[(size_t)s[j] * 8 + q];   // j>=rem -> row 0 (masked)
#pragma unroll
            for (int j = 0; j < 8; ++j)
                if (j < rem) bfacc(uu[j], alo, ahi);
        }
    }
    if (node < NN) {                            // relu'd row -> LDS (all lanes)
        float4 b0v = b4[2 * q], b1v = b4[2 * q + 1];
        float4 r0, r1;
        r0.x = fmaxf(alo.x * dv + b0v.x, 0.f);
        r0.y = fmaxf(alo.y * dv + b0v.y, 0.f);
        r0.z = fmaxf(alo.z * dv + b0v.z, 0.f);
        r0.w = fmaxf(alo.w * dv + b0v.w, 0.f);
        r1.x = fmaxf(ahi.x * dv + b1v.x, 0.f);
        r1.y = fmaxf(ahi.y * dv + b1v.y, 0.f);
        r1.z = fmaxf(ahi.z * dv + b1v.z, 0.f);
        r1.w = fmaxf(ahi.w * dv + b1v.w, 0.f);
        *(float4*)&rows[nl * LDW + 8 * q]     = r0;
        *(float4*)&rows[nl * LDW + 8 * q + 4] = r1;
        if (MODE == 1) {
            out0[(size_t)node * 16 + 2 * q]     = r0;
            out0[(size_t)node * 16 + 2 * q + 1] = r1;
        }
        if (q == 0) dvs[nl] = dv;
    }
    __syncthreads();                           // the only barrier

    // ---- phase 2: rows @ Ws, k_gemm pattern (2 rows x 4 cols / thread) ----
    int tc = (t & 15) * 4;
    int rbase = t >> 4;                        // rows rbase, rbase+16
    float4 a0 = make_float4(0.f, 0.f, 0.f, 0.f);
    float4 a1 = make_float4(0.f, 0.f, 0.f, 0.f);
#pragma unroll 1
    for (int k = 0; k < 64; k += 4) {
        float4 wv[4];
#pragma unroll
        for (int kk = 0; kk < 4; ++kk)
            wv[kk] = *(const float4*)&Ws[(k + kk) * LDW + tc];
        float4 x0 = *(const float4*)&rows[rbase * LDW + k];
        float4 x1 = *(const float4*)&rows[(rbase + 16) * LDW + k];
        a0.x += x0.x * wv[0].x + x0.y * wv[1].x + x0.z * wv[2].x + x0.w * wv[3].x;
        a0.y += x0.x * wv[0].y + x0.y * wv[1].y + x0.z * wv[2].y + x0.w * wv[3].y;
        a0.z += x0.x * wv[0].z + x0.y * wv[1].z + x0.z * wv[2].z + x0.w * wv[3].z;
        a0.w += x0.x * wv[0].w + x0.y * wv[1].w + x0.z * wv[2].w + x0.w * wv[3].w;
        a1.x += x1.x * wv[0].x + x1.y * wv[1].x + x1.z * wv[2].x + x1.w * wv[3].x;
        a1.y += x1.x * wv[0].y + x1.y * wv[1].y + x1.z * wv[2].y + x1.w * wv[3].y;
        a1.z += x1.x * wv[0].z + x1.y * wv[1].z + x1.z * wv[2].z + x1.w * wv[3].z;
        a1.w += x1.x * wv[0].w + x1.y * wv[1].w + x1.z * wv[2].w + x1.w * wv[3].w;
    }
    int n0 = base + rbase, n1 = base + rbase + 16;
    if (MODE == 0) {
        if (n0 < NN) {
            float s = dvs[rbase];
            ushort4 p;
            p.x = f2bf(a0.x * s); p.y = f2bf(a0.y * s);
            p.z = f2bf(a0.z * s); p.w = f2bf(a0.w * s);
            *(ushort4*)&HbOut[(size_t)n0 * 64 + tc] = p;
        }
        if (n1 < NN) {
            float s = dvs[rbase + 16];
            ushort4 p;
            p.x = f2bf(a1.x * s); p.y = f2bf(a1.y * s);
            p.z = f2bf(a1.z * s); p.w = f2bf(a1.w * s);
            *(ushort4*)&HbOut[(size_t)n1 * 64 + tc] = p;
        }
    } else {
        float4 bv = *(const float4*)&bls[tc];
        if (n0 < NN) {
            float4 o; o.x = a0.x + bv.x; o.y = a0.y + bv.y;
            o.z = a0.z + bv.z; o.w = a0.w + bv.w;
            *(float4*)&out1[(size_t)n0 * 64 + tc] = o;
        }
        if (n1 < NN) {
            float4 o; o.x = a1.x + bv.x; o.y = a1.y + bv.y;
            o.z = a1.z + bv.z; o.w = a1.w + bv.w;
            *(float4*)&out1[(size_t)n1 * 64 + tc] = o;
        }
    }
}

extern "C" void kernel_launch(void* const* d_in, const int* in_sizes, int n_in,
                              void* d_out, int out_size, void* d_ws, size_t ws_size,
                              hipStream_t stream) {
    const float* x  = (const float*)d_in[0];
    const void*  ei = d_in[1];               // edge_index, dtype detected on device
    const float* W0 = (const float*)d_in[3];
    const float* b0 = (const float*)d_in[4];
    const float* W1 = (const float*)d_in[5];
    const float* b1 = (const float*)d_in[6];
    const float* W2 = (const float*)d_in[7];
    const float* b2 = (const float*)d_in[8];
    const float* Wl = (const float*)d_in[9];
    const float* bl = (const float*)d_in[10];

    char* ws = (char*)d_ws;
    int*      flag    = (int*)(ws);
    int*      bcnt    = (int*)(ws + 256);
    int*      offs    = (int*)(ws + 4352);        // 783 ints
    int*      curs    = (int*)(ws + 8448);        // 782 ints
    float*    dinv    = (float*)(ws + 12544);     // 400000 B
    int*      noffs   = (int*)(ws + 412672);      // 100001 ints
    int*      csr_src = (int*)(ws + 812800);      // 3.2 MB
    unsigned short* HbA = (unsigned short*)(ws + 4100096);    // 12.8 MB
    unsigned short* HbB = (unsigned short*)(ws + 16900096);   // 12.8 MB

    float* out0 = (float*)d_out;             // graded relu output (h3)
    float* out1 = out0 + (size_t)NN * HD;    // graded linear output
    unsigned* ebuf = (unsigned*)out1;        // bucket-major edges; dies pre-GEMM0

    int gG = (NN + 127) / 128;               // 782 gemm blocks
    int gF = (NN + 31) / 32;                 // 3125 fused blocks (32 nodes each)

    // ---- preprocessing: bucket bin + in-bucket counting sort -> CSR ----
    k_initdet<<<1, 1024, 0, stream>>>(ei, bcnt, flag);
    k_pass0<<<128, 256, 0, stream>>>(ei, flag, bcnt);
    k_scan1<<<1, 256, 0, stream>>>(bcnt, offs, curs);
    k_passA<<<PA_NB, 256, 0, stream>>>(ei, flag, curs, ebuf);
    k_passB<<<NBUCK, 256, 0, stream>>>(ebuf, offs, noffs, csr_src, dinv);

    // ---- layer 0 GEMM: HbA = dinv * (x @ W0), bf16 ----
    k_gemm<false, true, true><<<gG, 256, 0, stream>>>(x, W0, nullptr, dinv,
                                                      (void*)HbA, NN);
    // ---- fused layer 1: agg(HbA)+b0+relu, @W1*dinv -> HbB ----
    k_fused<0><<<gF, 256, 0, stream>>>((const uint4*)HbA, noffs, csr_src, dinv,
                                       (const float4*)b0, W1, nullptr,
                                       HbB, nullptr, nullptr);
    // ---- fused layer 2: agg(HbB)+b1+relu, @W2*dinv -> HbA ----
    k_fused<0><<<gF, 256, 0, stream>>>((const uint4*)HbB, noffs, csr_src, dinv,
                                       (const float4*)b1, W2, nullptr,
                                       HbA, nullptr, nullptr);
    // ---- fused final: agg(HbA)+b2+relu -> out0 ; row@Wl+bl -> out1 ----
    k_fused<1><<<gF, 256, 0, stream>>>((const uint4*)HbA, noffs, csr_src, dinv,
                                       (const float4*)b2, Wl, bl,
                                       nullptr, (float4*)out0, out1);
}